// Round 1
// baseline (124.052 us; speedup 1.0000x reference)
//
#include <hip/hip_runtime.h>

// Problem constants (fixed by setup_inputs)
#define B   8
#define C   256
#define H   128
#define W   128
#define FH  512
#define FW  512

// ---------------------------------------------------------------------------
// Kernel 1: strided 4x4 conv downsample of flows using runtime conv_w.
// f[b,o,y,x] = sum_{i,kh,kw} flows[b,i,4y+kh,4x+kw] * conv_w[o,i,kh,kw]
// One thread per output element of f (B*2*H*W = 262144).
// ---------------------------------------------------------------------------
__global__ __launch_bounds__(256) void downsample_kernel(
    const float* __restrict__ flows,
    const float* __restrict__ conv_w,
    float* __restrict__ f)
{
    int idx = blockIdx.x * blockDim.x + threadIdx.x;
    if (idx >= B * 2 * H * W) return;
    int x = idx & (W - 1);
    int y = (idx >> 7) & (H - 1);
    int o = (idx >> 14) & 1;
    int b = idx >> 15;

    const float* fb = flows + (size_t)b * 2 * FH * FW;
    const float* cw = conv_w + o * 2 * 16;   // conv_w[o, :, :, :]

    float acc = 0.f;
#pragma unroll
    for (int i = 0; i < 2; ++i) {
        const float* fi = fb + (size_t)i * FH * FW;
#pragma unroll
        for (int kh = 0; kh < 4; ++kh) {
            const float4 v = *reinterpret_cast<const float4*>(
                fi + (size_t)(4 * y + kh) * FW + 4 * x);
            const float* w = cw + i * 16 + kh * 4;
            acc += v.x * w[0] + v.y * w[1] + v.z * w[2] + v.w * w[3];
        }
    }
    f[idx] = acc;   // layout [B,2,H,W]
}

// ---------------------------------------------------------------------------
// Kernel 2: bilinear warp.
// Each block: one batch, 64 consecutive pixels, all 256 channels.
// Phase 1: 64 lanes compute 4 clipped indices + 4 masked weights -> LDS.
// Phase 2: 4 waves (channel offsets 0..3) loop c in steps of 4;
//          per-thread index/weight data hoisted to registers.
// ---------------------------------------------------------------------------
#define PPB 64   // pixels per block

__global__ __launch_bounds__(256) void warp_kernel(
    const float* __restrict__ feat,
    const float* __restrict__ f,
    float* __restrict__ out)
{
    __shared__ int   s_idx[4][PPB];
    __shared__ float s_w[4][PPB];

    const int tid = threadIdx.x;
    const int blocks_per_img = (H * W) / PPB;          // 256
    const int b = blockIdx.x / blocks_per_img;
    const int pix_base = (blockIdx.x % blocks_per_img) * PPB;

    if (tid < PPB) {
        const int p = pix_base + tid;
        const int x = p & (W - 1);
        const int y = p >> 7;
        const float fx = f[(size_t)(b * 2 + 0) * H * W + p];
        const float fy = f[(size_t)(b * 2 + 1) * H * W + p];
        const float gx = (float)x + fx;
        const float gy = (float)y + fy;
        const float x0f = floorf(gx);
        const float y0f = floorf(gy);
        const float wx = gx - x0f;
        const float wy = gy - y0f;
        const int x0 = (int)x0f, y0 = (int)y0f;
        const int x1 = x0 + 1,  y1 = y0 + 1;

        const bool vx0 = (x0 >= 0) && (x0 < W);
        const bool vx1 = (x1 >= 0) && (x1 < W);
        const bool vy0 = (y0 >= 0) && (y0 < H);
        const bool vy1 = (y1 >= 0) && (y1 < H);

        const int cx0 = min(max(x0, 0), W - 1);
        const int cx1 = min(max(x1, 0), W - 1);
        const int cy0 = min(max(y0, 0), H - 1);
        const int cy1 = min(max(y1, 0), H - 1);

        s_idx[0][tid] = cy0 * W + cx0;
        s_idx[1][tid] = cy0 * W + cx1;
        s_idx[2][tid] = cy1 * W + cx0;
        s_idx[3][tid] = cy1 * W + cx1;
        s_w[0][tid] = (vx0 && vy0) ? (1.f - wx) * (1.f - wy) : 0.f;
        s_w[1][tid] = (vx1 && vy0) ? wx * (1.f - wy)         : 0.f;
        s_w[2][tid] = (vx0 && vy1) ? (1.f - wx) * wy         : 0.f;
        s_w[3][tid] = (vx1 && vy1) ? wx * wy                 : 0.f;
    }
    __syncthreads();

    const int pl   = tid & (PPB - 1);   // pixel lane (constant across c-loop)
    const int cofs = tid >> 6;          // wave id -> channel offset 0..3

    const int   i0 = s_idx[0][pl], i1 = s_idx[1][pl];
    const int   i2 = s_idx[2][pl], i3 = s_idx[3][pl];
    const float w0 = s_w[0][pl],   w1 = s_w[1][pl];
    const float w2 = s_w[2][pl],   w3 = s_w[3][pl];

    const float* fb = feat + (size_t)b * C * H * W;
    float*       ob = out  + (size_t)b * C * H * W + pix_base;

#pragma unroll 4
    for (int c0 = 0; c0 < C; c0 += 4) {
        const int c = c0 + cofs;
        const float* fc = fb + (size_t)c * H * W;
        const float v = fc[i0] * w0 + fc[i1] * w1 + fc[i2] * w2 + fc[i3] * w3;
        ob[(size_t)c * H * W + pl] = v;
    }
}

// ---------------------------------------------------------------------------
extern "C" void kernel_launch(void* const* d_in, const int* in_sizes, int n_in,
                              void* d_out, int out_size, void* d_ws, size_t ws_size,
                              hipStream_t stream)
{
    const float* features = (const float*)d_in[0];
    const float* flows    = (const float*)d_in[1];
    const float* conv_w   = (const float*)d_in[2];
    float*       out      = (float*)d_out;
    float*       f        = (float*)d_ws;   // [B,2,H,W] = 1 MiB

    // Kernel 1: 262144 outputs / 256 = 1024 blocks
    downsample_kernel<<<1024, 256, 0, stream>>>(flows, conv_w, f);

    // Kernel 2: B * (H*W/PPB) = 8 * 256 = 2048 blocks
    warp_kernel<<<2048, 256, 0, stream>>>(features, f, out);
}

// Round 2
// 112.093 us; speedup vs baseline: 1.1067x; 1.1067x over previous
//
#include <hip/hip_runtime.h>

// Problem constants (fixed by setup_inputs)
#define B   8
#define C   256
#define H   128
#define W   128
#define HW  (H * W)
#define FH  512
#define FW  512

// ---------------------------------------------------------------------------
// Kernel 1: strided 4x4 conv downsample of flows using runtime conv_w.
// f[b,o,y,x] = sum_{i,kh,kw} flows[b,i,4y+kh,4x+kw] * conv_w[o,i,kh,kw]
// ---------------------------------------------------------------------------
__global__ __launch_bounds__(256) void downsample_kernel(
    const float* __restrict__ flows,
    const float* __restrict__ conv_w,
    float* __restrict__ f)
{
    int idx = blockIdx.x * blockDim.x + threadIdx.x;
    if (idx >= B * 2 * H * W) return;
    int x = idx & (W - 1);
    int y = (idx >> 7) & (H - 1);
    int o = (idx >> 14) & 1;
    int b = idx >> 15;

    const float* fb = flows + (size_t)b * 2 * FH * FW;
    const float* cw = conv_w + o * 2 * 16;

    float acc = 0.f;
#pragma unroll
    for (int i = 0; i < 2; ++i) {
        const float* fi = fb + (size_t)i * FH * FW;
#pragma unroll
        for (int kh = 0; kh < 4; ++kh) {
            const float4 v = *reinterpret_cast<const float4*>(
                fi + (size_t)(4 * y + kh) * FW + 4 * x);
            const float* w = cw + i * 16 + kh * 4;
            acc += v.x * w[0] + v.y * w[1] + v.z * w[2] + v.w * w[3];
        }
    }
    f[idx] = acc;
}

// ---------------------------------------------------------------------------
// Kernel 2: bilinear warp.
// Block = one batch, 64 consecutive pixels, all 256 channels.
// XCD-chunked swizzle: logical = (hw%8)*256 + hw/8  ->  each XCD owns one
// batch (256 contiguous row-segment blocks share that XCD's L2).
// ---------------------------------------------------------------------------
#define PPB 64   // pixels per block

__global__ __launch_bounds__(256, 8) void warp_kernel(
    const float* __restrict__ feat,
    const float* __restrict__ f,
    float* __restrict__ out)
{
    __shared__ int   s_idx[4][PPB];
    __shared__ float s_w[4][PPB];

    // XCD-aware swizzle (2048 blocks, 8 XCDs, 256 blocks/XCD = 1 batch)
    const int hw_bid = blockIdx.x;
    const int bid = (hw_bid & 7) * 256 + (hw_bid >> 3);

    const int tid = threadIdx.x;
    const int blocks_per_img = (H * W) / PPB;          // 256
    const int b = bid / blocks_per_img;                // == hw_bid & 7
    const int pix_base = (bid % blocks_per_img) * PPB;

    if (tid < PPB) {
        const int p = pix_base + tid;
        const int x = p & (W - 1);
        const int y = p >> 7;
        const float fx = f[(size_t)(b * 2 + 0) * HW + p];
        const float fy = f[(size_t)(b * 2 + 1) * HW + p];
        const float gx = (float)x + fx;
        const float gy = (float)y + fy;
        const float x0f = floorf(gx);
        const float y0f = floorf(gy);
        const float wx = gx - x0f;
        const float wy = gy - y0f;
        const int x0 = (int)x0f, y0 = (int)y0f;
        const int x1 = x0 + 1,  y1 = y0 + 1;

        const bool vx0 = (x0 >= 0) && (x0 < W);
        const bool vx1 = (x1 >= 0) && (x1 < W);
        const bool vy0 = (y0 >= 0) && (y0 < H);
        const bool vy1 = (y1 >= 0) && (y1 < H);

        const int cx0 = min(max(x0, 0), W - 1);
        const int cx1 = min(max(x1, 0), W - 1);
        const int cy0 = min(max(y0, 0), H - 1);
        const int cy1 = min(max(y1, 0), H - 1);

        s_idx[0][tid] = cy0 * W + cx0;
        s_idx[1][tid] = cy0 * W + cx1;
        s_idx[2][tid] = cy1 * W + cx0;
        s_idx[3][tid] = cy1 * W + cx1;
        s_w[0][tid] = (vx0 && vy0) ? (1.f - wx) * (1.f - wy) : 0.f;
        s_w[1][tid] = (vx1 && vy0) ? wx * (1.f - wy)         : 0.f;
        s_w[2][tid] = (vx0 && vy1) ? (1.f - wx) * wy         : 0.f;
        s_w[3][tid] = (vx1 && vy1) ? wx * wy                 : 0.f;
    }
    __syncthreads();

    const int pl   = tid & (PPB - 1);   // pixel lane
    const int cofs = tid >> 6;          // wave id -> channel offset 0..3

    const int   i0 = s_idx[0][pl], i1 = s_idx[1][pl];
    const int   i2 = s_idx[2][pl], i3 = s_idx[3][pl];
    const float w0 = s_w[0][pl],   w1 = s_w[1][pl];
    const float w2 = s_w[2][pl],   w3 = s_w[3][pl];

    const float* fb = feat + (size_t)b * C * HW;
    float*       ob = out  + (size_t)b * C * HW + pix_base;

    const float* p = fb + (size_t)cofs * HW;
    float*       q = ob + (size_t)cofs * HW + pl;

    // 64 iterations: wave handles channels cofs, cofs+4, ..., cofs+252.
    // unroll 8 -> 32 independent loads clustered per unrolled body.
#pragma unroll 8
    for (int k = 0; k < C / 4; ++k) {
        const float v = p[i0] * w0 + p[i1] * w1 + p[i2] * w2 + p[i3] * w3;
        __builtin_nontemporal_store(v, q);
        p += 4 * HW;
        q += 4 * HW;
    }
}

// ---------------------------------------------------------------------------
extern "C" void kernel_launch(void* const* d_in, const int* in_sizes, int n_in,
                              void* d_out, int out_size, void* d_ws, size_t ws_size,
                              hipStream_t stream)
{
    const float* features = (const float*)d_in[0];
    const float* flows    = (const float*)d_in[1];
    const float* conv_w   = (const float*)d_in[2];
    float*       out      = (float*)d_out;
    float*       f        = (float*)d_ws;   // [B,2,H,W] = 1 MiB

    downsample_kernel<<<1024, 256, 0, stream>>>(flows, conv_w, f);
    warp_kernel<<<2048, 256, 0, stream>>>(features, f, out);
}

// Round 3
// 99.853 us; speedup vs baseline: 1.2423x; 1.1226x over previous
//
#include <hip/hip_runtime.h>

// Problem constants (fixed by setup_inputs)
#define B   8
#define C   256
#define H   128
#define W   128
#define HW  (H * W)
#define FH  512
#define FW  512

// 8-byte load at 4-byte-aligned address. aligned(4) keeps codegen correct
// regardless of whether gfx950 emits dwordx2 or splits into 2 dwords.
struct __attribute__((packed, aligned(4))) pf2 { float x, y; };

// ---------------------------------------------------------------------------
// Kernel 1: strided 4x4 conv downsample of flows using runtime conv_w.
// ---------------------------------------------------------------------------
__global__ __launch_bounds__(256) void downsample_kernel(
    const float* __restrict__ flows,
    const float* __restrict__ conv_w,
    float* __restrict__ f)
{
    int idx = blockIdx.x * blockDim.x + threadIdx.x;
    if (idx >= B * 2 * H * W) return;
    int x = idx & (W - 1);
    int y = (idx >> 7) & (H - 1);
    int o = (idx >> 14) & 1;
    int b = idx >> 15;

    const float* fb = flows + (size_t)b * 2 * FH * FW;
    const float* cw = conv_w + o * 2 * 16;

    float acc = 0.f;
#pragma unroll
    for (int i = 0; i < 2; ++i) {
        const float* fi = fb + (size_t)i * FH * FW;
#pragma unroll
        for (int kh = 0; kh < 4; ++kh) {
            const float4 v = *reinterpret_cast<const float4*>(
                fi + (size_t)(4 * y + kh) * FW + 4 * x);
            const float* w = cw + i * 16 + kh * 4;
            acc += v.x * w[0] + v.y * w[1] + v.z * w[2] + v.w * w[3];
        }
    }
    f[idx] = acc;
}

// ---------------------------------------------------------------------------
// Kernel 2: bilinear warp, pair-load formulation.
// Per pixel we precompute, for each of the two source rows, a base index
// (clamped so [base, base+1] is row-interior) and pair weights (a,b) with all
// x/y clamp+validity folded in. Inner loop per channel: two 8B loads + 4 FMA.
// ---------------------------------------------------------------------------
#define PPB 64   // pixels per block

__global__ __launch_bounds__(256, 6) void warp_kernel(
    const float* __restrict__ feat,
    const float* __restrict__ f,
    float* __restrict__ out)
{
    __shared__ int   s_i0[PPB], s_i1[PPB];
    __shared__ float s_a0[PPB], s_b0[PPB], s_a1[PPB], s_b1[PPB];

    // XCD-aware swizzle (2048 blocks, 8 XCDs): each XCD owns one batch image.
    const int hw_bid = blockIdx.x;
    const int bid = (hw_bid & 7) * 256 + (hw_bid >> 3);

    const int tid = threadIdx.x;
    const int blocks_per_img = HW / PPB;               // 256
    const int b = bid / blocks_per_img;
    const int pix_base = (bid % blocks_per_img) * PPB;

    if (tid < PPB) {
        const int p = pix_base + tid;
        const int x = p & (W - 1);
        const int y = p >> 7;
        const float fx = f[(size_t)(b * 2 + 0) * HW + p];
        const float fy = f[(size_t)(b * 2 + 1) * HW + p];
        const float gx = (float)x + fx;
        const float gy = (float)y + fy;
        const float x0f = floorf(gx);
        const float y0f = floorf(gy);
        const float wx = gx - x0f;
        const float wy = gy - y0f;
        const int x0 = (int)x0f, y0 = (int)y0f;
        const int y1 = y0 + 1;

        // x-case: map corner weights (1-wx, wx) onto the aligned-ish pair
        // (f[base], f[base+1]) with base = clamp(x0, 0, W-2).
        const float u0 = 1.f - wx, u1 = wx;
        float A, Bv;
        if (x0 >= 0 && x0 <= W - 2)      { A = u0;  Bv = u1;  }  // both corners in pair
        else if (x0 == W - 1)            { A = 0.f; Bv = u0;  }  // c0 = pair.y
        else if (x0 == -1)               { A = u1;  Bv = 0.f; }  // c1 = pair.x
        else                             { A = 0.f; Bv = 0.f; }  // fully OOB
        const int bx = min(max(x0, 0), W - 2);

        const float vy0 = (y0 >= 0 && y0 < H) ? 1.f : 0.f;
        const float vy1 = (y1 >= 0 && y1 < H) ? 1.f : 0.f;
        const int cy0 = min(max(y0, 0), H - 1);
        const int cy1 = min(max(y1, 0), H - 1);

        s_i0[tid] = cy0 * W + bx;
        s_i1[tid] = cy1 * W + bx;
        const float wy0 = (1.f - wy) * vy0;
        const float wy1 = wy * vy1;
        s_a0[tid] = A * wy0;  s_b0[tid] = Bv * wy0;
        s_a1[tid] = A * wy1;  s_b1[tid] = Bv * wy1;
    }
    __syncthreads();

    const int pl   = tid & (PPB - 1);   // pixel lane
    const int cofs = tid >> 6;          // wave id -> channel offset 0..3

    const int   i0 = s_i0[pl], i1 = s_i1[pl];
    const float a0 = s_a0[pl], b0 = s_b0[pl];
    const float a1 = s_a1[pl], b1 = s_b1[pl];

    const float* fb = feat + (size_t)b * C * HW;
    float*       ob = out  + (size_t)b * C * HW + pix_base;

    const float* p = fb + (size_t)cofs * HW;
    float*       q = ob + (size_t)cofs * HW + pl;

#pragma unroll 8
    for (int k = 0; k < C / 4; ++k) {
        const pf2 r0 = *reinterpret_cast<const pf2*>(p + i0);
        const pf2 r1 = *reinterpret_cast<const pf2*>(p + i1);
        *q = r0.x * a0 + r0.y * b0 + r1.x * a1 + r1.y * b1;
        p += 4 * HW;
        q += 4 * HW;
    }
}

// ---------------------------------------------------------------------------
extern "C" void kernel_launch(void* const* d_in, const int* in_sizes, int n_in,
                              void* d_out, int out_size, void* d_ws, size_t ws_size,
                              hipStream_t stream)
{
    const float* features = (const float*)d_in[0];
    const float* flows    = (const float*)d_in[1];
    const float* conv_w   = (const float*)d_in[2];
    float*       out      = (float*)d_out;
    float*       f        = (float*)d_ws;   // [B,2,H,W] = 1 MiB

    downsample_kernel<<<1024, 256, 0, stream>>>(flows, conv_w, f);
    warp_kernel<<<2048, 256, 0, stream>>>(features, f, out);
}

// Round 4
// 97.934 us; speedup vs baseline: 1.2667x; 1.0196x over previous
//
#include <hip/hip_runtime.h>

// Problem constants (fixed by setup_inputs)
#define B   8
#define C   256
#define H   128
#define W   128
#define HW  (H * W)
#define FH  512
#define FW  512

// 8-byte load at 4-byte-aligned address.
struct __attribute__((packed, aligned(4))) pf2 { float x, y; };

// ---------------------------------------------------------------------------
// Kernel 1: strided 4x4 conv downsample of flows using runtime conv_w.
// ---------------------------------------------------------------------------
__global__ __launch_bounds__(256) void downsample_kernel(
    const float* __restrict__ flows,
    const float* __restrict__ conv_w,
    float* __restrict__ f)
{
    int idx = blockIdx.x * blockDim.x + threadIdx.x;
    if (idx >= B * 2 * H * W) return;
    int x = idx & (W - 1);
    int y = (idx >> 7) & (H - 1);
    int o = (idx >> 14) & 1;
    int b = idx >> 15;

    const float* fb = flows + (size_t)b * 2 * FH * FW;
    const float* cw = conv_w + o * 2 * 16;

    float acc = 0.f;
#pragma unroll
    for (int i = 0; i < 2; ++i) {
        const float* fi = fb + (size_t)i * FH * FW;
#pragma unroll
        for (int kh = 0; kh < 4; ++kh) {
            const float4 v = *reinterpret_cast<const float4*>(
                fi + (size_t)(4 * y + kh) * FW + 4 * x);
            const float* w = cw + i * 16 + kh * 4;
            acc += v.x * w[0] + v.y * w[1] + v.z * w[2] + v.w * w[3];
        }
    }
    f[idx] = acc;
}

// ---------------------------------------------------------------------------
// Kernel 2: bilinear warp, pair-load + manual 8-deep load batching.
// Phase A of each chunk: issue 16 gather loads into named registers.
// Phase B: compute + coalesced stores. Keeps ~16 loads in flight per wave.
// ---------------------------------------------------------------------------
#define PPB 64   // pixels per block
#define UN  8    // channel-steps batched per chunk

__global__ __launch_bounds__(256, 4) void warp_kernel(
    const float* __restrict__ feat,
    const float* __restrict__ f,
    float* __restrict__ out)
{
    __shared__ int   s_i0[PPB], s_i1[PPB];
    __shared__ float s_a0[PPB], s_b0[PPB], s_a1[PPB], s_b1[PPB];

    // XCD-aware swizzle (2048 blocks, 8 XCDs): each XCD owns one batch image.
    const int hw_bid = blockIdx.x;
    const int bid = (hw_bid & 7) * 256 + (hw_bid >> 3);

    const int tid = threadIdx.x;
    const int blocks_per_img = HW / PPB;               // 256
    const int b = bid / blocks_per_img;
    const int pix_base = (bid % blocks_per_img) * PPB;

    if (tid < PPB) {
        const int p = pix_base + tid;
        const int x = p & (W - 1);
        const int y = p >> 7;
        const float fx = f[(size_t)(b * 2 + 0) * HW + p];
        const float fy = f[(size_t)(b * 2 + 1) * HW + p];
        const float gx = (float)x + fx;
        const float gy = (float)y + fy;
        const float x0f = floorf(gx);
        const float y0f = floorf(gy);
        const float wx = gx - x0f;
        const float wy = gy - y0f;
        const int x0 = (int)x0f, y0 = (int)y0f;
        const int y1 = y0 + 1;

        const float u0 = 1.f - wx, u1 = wx;
        float A, Bv;
        if (x0 >= 0 && x0 <= W - 2)      { A = u0;  Bv = u1;  }
        else if (x0 == W - 1)            { A = 0.f; Bv = u0;  }
        else if (x0 == -1)               { A = u1;  Bv = 0.f; }
        else                             { A = 0.f; Bv = 0.f; }
        const int bx = min(max(x0, 0), W - 2);

        const float vy0 = (y0 >= 0 && y0 < H) ? 1.f : 0.f;
        const float vy1 = (y1 >= 0 && y1 < H) ? 1.f : 0.f;
        const int cy0 = min(max(y0, 0), H - 1);
        const int cy1 = min(max(y1, 0), H - 1);

        s_i0[tid] = cy0 * W + bx;
        s_i1[tid] = cy1 * W + bx;
        const float wy0 = (1.f - wy) * vy0;
        const float wy1 = wy * vy1;
        s_a0[tid] = A * wy0;  s_b0[tid] = Bv * wy0;
        s_a1[tid] = A * wy1;  s_b1[tid] = Bv * wy1;
    }
    __syncthreads();

    const int pl   = tid & (PPB - 1);   // pixel lane
    const int cofs = tid >> 6;          // wave id -> channel offset 0..3

    const int   i0 = s_i0[pl], i1 = s_i1[pl];
    const float a0 = s_a0[pl], b0 = s_b0[pl];
    const float a1 = s_a1[pl], b1 = s_b1[pl];

    const float* fb = feat + (size_t)b * C * HW;
    float*       ob = out  + (size_t)b * C * HW + pix_base;

    const float* p = fb + (size_t)cofs * HW;
    float*       q = ob + (size_t)cofs * HW + pl;

    // 64 channel-steps total; process in chunks of UN with all loads issued
    // before any use (static indexing -> registers, not scratch).
    for (int k = 0; k < C / 4; k += UN) {
        pf2 r0[UN], r1[UN];
#pragma unroll
        for (int u = 0; u < UN; ++u) {
            const float* pc = p + (size_t)(k + u) * 4 * HW;
            r0[u] = *reinterpret_cast<const pf2*>(pc + i0);
            r1[u] = *reinterpret_cast<const pf2*>(pc + i1);
        }
#pragma unroll
        for (int u = 0; u < UN; ++u) {
            q[(size_t)(k + u) * 4 * HW] =
                r0[u].x * a0 + r0[u].y * b0 + r1[u].x * a1 + r1[u].y * b1;
        }
    }
}

// ---------------------------------------------------------------------------
extern "C" void kernel_launch(void* const* d_in, const int* in_sizes, int n_in,
                              void* d_out, int out_size, void* d_ws, size_t ws_size,
                              hipStream_t stream)
{
    const float* features = (const float*)d_in[0];
    const float* flows    = (const float*)d_in[1];
    const float* conv_w   = (const float*)d_in[2];
    float*       out      = (float*)d_out;
    float*       f        = (float*)d_ws;   // [B,2,H,W] = 1 MiB

    downsample_kernel<<<1024, 256, 0, stream>>>(flows, conv_w, f);
    warp_kernel<<<2048, 256, 0, stream>>>(features, f, out);
}

// Round 5
// 94.176 us; speedup vs baseline: 1.3172x; 1.0399x over previous
//
#include <hip/hip_runtime.h>

// Problem constants (fixed by setup_inputs)
#define B   8
#define C   256
#define H   128
#define W   128
#define HW  (H * W)
#define FH  512
#define FW  512

// 8-byte load at 4-byte-aligned address.
struct __attribute__((packed, aligned(4))) pf2 { float x, y; };

// ---------------------------------------------------------------------------
// Kernel 1: strided 4x4 conv downsample of flows using runtime conv_w.
// ---------------------------------------------------------------------------
__global__ __launch_bounds__(256) void downsample_kernel(
    const float* __restrict__ flows,
    const float* __restrict__ conv_w,
    float* __restrict__ f)
{
    int idx = blockIdx.x * blockDim.x + threadIdx.x;
    if (idx >= B * 2 * H * W) return;
    int x = idx & (W - 1);
    int y = (idx >> 7) & (H - 1);
    int o = (idx >> 14) & 1;
    int b = idx >> 15;

    const float* fb = flows + (size_t)b * 2 * FH * FW;
    const float* cw = conv_w + o * 2 * 16;

    float acc = 0.f;
#pragma unroll
    for (int i = 0; i < 2; ++i) {
        const float* fi = fb + (size_t)i * FH * FW;
#pragma unroll
        for (int kh = 0; kh < 4; ++kh) {
            const float4 v = *reinterpret_cast<const float4*>(
                fi + (size_t)(4 * y + kh) * FW + 4 * x);
            const float* w = cw + i * 16 + kh * 4;
            acc += v.x * w[0] + v.y * w[1] + v.z * w[2] + v.w * w[3];
        }
    }
    f[idx] = acc;
}

// ---------------------------------------------------------------------------
// Kernel 2: bilinear warp, pair-load, FORCED load clustering.
// Each chunk: issue 16 gather loads, sched_barrier(0) pins them before any
// use; scheduler may still hoist next chunk's loads over this chunk's math.
// ---------------------------------------------------------------------------
#define PPB 64   // pixels per block
#define UN  8    // channel-steps batched per chunk

__global__ __launch_bounds__(256, 4) void warp_kernel(
    const float* __restrict__ feat,
    const float* __restrict__ f,
    float* __restrict__ out)
{
    __shared__ int   s_i0[PPB], s_i1[PPB];
    __shared__ float s_a0[PPB], s_b0[PPB], s_a1[PPB], s_b1[PPB];

    // XCD-aware swizzle (2048 blocks, 8 XCDs): each XCD owns one batch image.
    const int hw_bid = blockIdx.x;
    const int bid = (hw_bid & 7) * 256 + (hw_bid >> 3);

    const int tid = threadIdx.x;
    const int blocks_per_img = HW / PPB;               // 256
    const int b = bid / blocks_per_img;
    const int pix_base = (bid % blocks_per_img) * PPB;

    if (tid < PPB) {
        const int p = pix_base + tid;
        const int x = p & (W - 1);
        const int y = p >> 7;
        const float fx = f[(size_t)(b * 2 + 0) * HW + p];
        const float fy = f[(size_t)(b * 2 + 1) * HW + p];
        const float gx = (float)x + fx;
        const float gy = (float)y + fy;
        const float x0f = floorf(gx);
        const float y0f = floorf(gy);
        const float wx = gx - x0f;
        const float wy = gy - y0f;
        const int x0 = (int)x0f, y0 = (int)y0f;
        const int y1 = y0 + 1;

        const float u0 = 1.f - wx, u1 = wx;
        float A, Bv;
        if (x0 >= 0 && x0 <= W - 2)      { A = u0;  Bv = u1;  }
        else if (x0 == W - 1)            { A = 0.f; Bv = u0;  }
        else if (x0 == -1)               { A = u1;  Bv = 0.f; }
        else                             { A = 0.f; Bv = 0.f; }
        const int bx = min(max(x0, 0), W - 2);

        const float vy0 = (y0 >= 0 && y0 < H) ? 1.f : 0.f;
        const float vy1 = (y1 >= 0 && y1 < H) ? 1.f : 0.f;
        const int cy0 = min(max(y0, 0), H - 1);
        const int cy1 = min(max(y1, 0), H - 1);

        s_i0[tid] = cy0 * W + bx;
        s_i1[tid] = cy1 * W + bx;
        const float wy0 = (1.f - wy) * vy0;
        const float wy1 = wy * vy1;
        s_a0[tid] = A * wy0;  s_b0[tid] = Bv * wy0;
        s_a1[tid] = A * wy1;  s_b1[tid] = Bv * wy1;
    }
    __syncthreads();

    const int pl   = tid & (PPB - 1);   // pixel lane
    const int cofs = tid >> 6;          // wave id -> channel offset 0..3

    const int   i0 = s_i0[pl], i1 = s_i1[pl];
    const float a0 = s_a0[pl], b0 = s_b0[pl];
    const float a1 = s_a1[pl], b1 = s_b1[pl];

    const float* fb = feat + (size_t)b * C * HW;
    float*       ob = out  + (size_t)b * C * HW + pix_base;

    const float* p = fb + (size_t)cofs * HW;
    float*       q = ob + (size_t)cofs * HW + pl;

    for (int k = 0; k < C / 4; k += UN) {
        pf2 r0[UN], r1[UN];
#pragma unroll
        for (int u = 0; u < UN; ++u) {
            const float* pc = p + (size_t)(k + u) * 4 * HW;
            r0[u] = *reinterpret_cast<const pf2*>(pc + i0);
            r1[u] = *reinterpret_cast<const pf2*>(pc + i1);
        }
        // Pin: all 16 loads of this chunk issue before any consumer below.
        __builtin_amdgcn_sched_barrier(0);
#pragma unroll
        for (int u = 0; u < UN; ++u) {
            q[(size_t)(k + u) * 4 * HW] =
                r0[u].x * a0 + r0[u].y * b0 + r1[u].x * a1 + r1[u].y * b1;
        }
    }
}

// ---------------------------------------------------------------------------
extern "C" void kernel_launch(void* const* d_in, const int* in_sizes, int n_in,
                              void* d_out, int out_size, void* d_ws, size_t ws_size,
                              hipStream_t stream)
{
    const float* features = (const float*)d_in[0];
    const float* flows    = (const float*)d_in[1];
    const float* conv_w   = (const float*)d_in[2];
    float*       out      = (float*)d_out;
    float*       f        = (float*)d_ws;   // [B,2,H,W] = 1 MiB

    downsample_kernel<<<1024, 256, 0, stream>>>(flows, conv_w, f);
    warp_kernel<<<2048, 256, 0, stream>>>(features, f, out);
}